// Round 4
// baseline (1292.745 us; speedup 1.0000x reference)
//
#include <hip/hip_runtime.h>
#include <hip/hip_bf16.h>
#include <math.h>

#define BSZ 4
#define NSEQ 2048
#define CDIM 1024
#define NH 16
#define DH 64
#define KC 64

typedef _Float16 half8_t __attribute__((ext_vector_type(8)));
typedef _Float16 half4_t __attribute__((ext_vector_type(4)));
typedef float floatx4 __attribute__((ext_vector_type(4)));

#define GLOBAL_AS(p) ((const __attribute__((address_space(1))) void*)(p))
#define LDS_AS(p)    ((__attribute__((address_space(3))) void*)(p))

// ---------------------------------------------------------------------------
// Prep: fp32 -> fp16 casts (weights transposed to [N][K])
// ---------------------------------------------------------------------------
__global__ __launch_bounds__(256) void cast_x_kernel(
    const float* __restrict__ src, _Float16* __restrict__ dst) {
  const size_t i = ((size_t)blockIdx.x * 256 + threadIdx.x) * 8;
  float4 a = *(const float4*)(src + i);
  float4 b = *(const float4*)(src + i + 4);
  half8_t h;
  h[0] = (_Float16)a.x; h[1] = (_Float16)a.y; h[2] = (_Float16)a.z; h[3] = (_Float16)a.w;
  h[4] = (_Float16)b.x; h[5] = (_Float16)b.y; h[6] = (_Float16)b.z; h[7] = (_Float16)b.w;
  *(half8_t*)(dst + i) = h;
}

__global__ __launch_bounds__(256) void transpose_cast_kernel(
    const float* __restrict__ src, _Float16* __restrict__ dst, int R, int C) {
  __shared__ float Ls[64][65];
  const int t = threadIdx.x;
  const int r0 = blockIdx.y * 64, c0 = blockIdx.x * 64;
  {
    const int lr = t >> 2, lcg = (t & 3) * 16;
    const float* s = src + (size_t)(r0 + lr) * C + c0 + lcg;
#pragma unroll
    for (int u = 0; u < 4; ++u)
      *(float4*)&Ls[lr][lcg + 4 * u] = *(const float4*)(s + 4 * u);
  }
  __syncthreads();
  const int c = t >> 2, rg = (t & 3) * 16;
  half8_t h0, h1;
#pragma unroll
  for (int u = 0; u < 8; ++u) h0[u] = (_Float16)Ls[rg + u][c];
#pragma unroll
  for (int u = 0; u < 8; ++u) h1[u] = (_Float16)Ls[rg + 8 + u][c];
  _Float16* d = dst + (size_t)(c0 + c) * R + r0 + rg;
  *(half8_t*)d = h0;
  *(half8_t*)(d + 8) = h1;
}

// ---------------------------------------------------------------------------
// Kernel 1: QKV GEMM (fp16 MFMA) + bias + RoPE epilogue (unchanged R3).
// ---------------------------------------------------------------------------
__global__ __launch_bounds__(256) void qkv_gemm_kernel(
    const _Float16* __restrict__ xh, const _Float16* __restrict__ Wt,
    const float* __restrict__ bias, _Float16* __restrict__ Qh,
    _Float16* __restrict__ Kh, _Float16* __restrict__ Vh) {
  __shared__ _Float16 As[128 * 64];
  __shared__ _Float16 Bs[128 * 64];
  const int tid = threadIdx.x;
  const int lane = tid & 63, w = tid >> 6;
  const int m = lane & 15, quad = lane >> 4;
  const int wr = (w >> 1) * 64, wc = (w & 1) * 64;
  const int m0 = blockIdx.y * 128;
  const int N0 = blockIdx.x * 128;
  const int sr = lane >> 3, sc = (lane & 7) * 8;

  floatx4 acc[4][4];
#pragma unroll
  for (int i = 0; i < 4; ++i)
#pragma unroll
    for (int j = 0; j < 4; ++j) acc[i][j] = (floatx4){0.f, 0.f, 0.f, 0.f};

  for (int k0 = 0; k0 < CDIM; k0 += 64) {
    __syncthreads();
#pragma unroll
    for (int i = 0; i < 4; ++i) {
      const int row = (w * 4 + i) * 8 + sr;
      __builtin_amdgcn_global_load_lds(
          GLOBAL_AS(xh + (size_t)(m0 + row) * CDIM + k0 + sc),
          LDS_AS(As + (w * 4 + i) * 512), 16, 0, 0);
      __builtin_amdgcn_global_load_lds(
          GLOBAL_AS(Wt + (size_t)(N0 + row) * CDIM + k0 + sc),
          LDS_AS(Bs + (w * 4 + i) * 512), 16, 0, 0);
    }
    __syncthreads();
#pragma unroll
    for (int ks = 0; ks < 2; ++ks) {
      half8_t af[4], bf[4];
#pragma unroll
      for (int mt = 0; mt < 4; ++mt)
        af[mt] = *(half8_t*)(As + (wr + mt * 16 + m) * 64 + ks * 32 + quad * 8);
#pragma unroll
      for (int nt = 0; nt < 4; ++nt)
        bf[nt] = *(half8_t*)(Bs + (wc + nt * 16 + m) * 64 + ks * 32 + quad * 8);
#pragma unroll
      for (int mt = 0; mt < 4; ++mt)
#pragma unroll
        for (int nt = 0; nt < 4; ++nt)
          acc[mt][nt] = __builtin_amdgcn_mfma_f32_16x16x32_f16(
              af[mt], bf[nt], acc[mt][nt], 0, 0, 0);
    }
  }

  const int F0 = N0 + wc;
  const int which = F0 >> 10;
  const int head = (F0 & 1023) >> 6;
  float bv[4];
#pragma unroll
  for (int nt = 0; nt < 4; ++nt) bv[nt] = bias[F0 + nt * 16 + m];

  if (which == 2) {
#pragma unroll
    for (int mt = 0; mt < 4; ++mt)
#pragma unroll
      for (int reg = 0; reg < 4; ++reg) {
        const int gm = m0 + wr + mt * 16 + 4 * quad + reg;
        const int b = gm >> 11, n = gm & 2047;
        const size_t vbase = ((size_t)(b * NH + head) * DH) * NSEQ + n;
#pragma unroll
        for (int nt = 0; nt < 4; ++nt)
          Vh[vbase + (size_t)(nt * 16 + m) * NSEQ] =
              (_Float16)(acc[mt][nt][reg] + bv[nt]);
      }
  } else {
    _Float16* dst = which ? Kh : Qh;
    const float qs = which ? 1.0f : 0.125f * 1.4426950408889634f;
    const float invfA = expf(-9.210340371976184f * ((float)m * (1.0f / 32.0f)));
    const float invfB = expf(-9.210340371976184f * ((float)(16 + m) * (1.0f / 32.0f)));
#pragma unroll
    for (int mt = 0; mt < 4; ++mt)
#pragma unroll
      for (int reg = 0; reg < 4; ++reg) {
        const int gm = m0 + wr + mt * 16 + 4 * quad + reg;
        const int b = gm >> 11, n = gm & 2047;
        float sA, cA, sB, cB;
        sincosf((float)n * invfA, &sA, &cA);
        sincosf((float)n * invfB, &sB, &cB);
        const size_t obase = ((size_t)(b * NH + head) * NSEQ + n) * DH;
#pragma unroll
        for (int nt = 0; nt < 4; ++nt) {
          const float val = acc[mt][nt][reg] + bv[nt];
          const float rot = (nt < 2) ? -(acc[mt][nt + 2][reg] + bv[nt + 2])
                                     :  (acc[mt][nt - 2][reg] + bv[nt - 2]);
          const float sv = (nt & 1) ? sB : sA;
          const float cv = (nt & 1) ? cB : cA;
          dst[obase + nt * 16 + m] = (_Float16)((val * cv + rot * sv) * qs);
        }
      }
  }
}

// ---------------------------------------------------------------------------
// Norm prepass: qn[row] = ||Qh row||  (Qh pre-scaled => log2-domain bound),
// kmax[bh] = max_n ||Kh row||  via atomicMax on uint bits (floats >= 0).
// 8 threads/row, 32 rows/block.
// ---------------------------------------------------------------------------
__global__ __launch_bounds__(64) void kmax_init_kernel(unsigned* kmaxu) {
  kmaxu[threadIdx.x] = 0u;
}

__global__ __launch_bounds__(256) void qk_norms_kernel(
    const _Float16* __restrict__ Qh, const _Float16* __restrict__ Kh,
    float* __restrict__ qn, unsigned* __restrict__ kmaxu) {
  const int tid = threadIdx.x;
  const size_t row = (size_t)blockIdx.x * 32 + (tid >> 3);
  const int c = (tid & 7) * 8;
  half8_t q8 = *(const half8_t*)(Qh + row * DH + c);
  half8_t k8 = *(const half8_t*)(Kh + row * DH + c);
  float qs = 0.f, ks = 0.f;
#pragma unroll
  for (int u = 0; u < 8; ++u) {
    const float qv = (float)q8[u], kv = (float)k8[u];
    qs += qv * qv; ks += kv * kv;
  }
  qs += __shfl_xor(qs, 1, 64); ks += __shfl_xor(ks, 1, 64);
  qs += __shfl_xor(qs, 2, 64); ks += __shfl_xor(ks, 2, 64);
  qs += __shfl_xor(qs, 4, 64); ks += __shfl_xor(ks, 4, 64);
  if ((tid & 7) == 0) {
    qn[row] = sqrtf(qs);
    atomicMax(&kmaxu[row >> 11], __float_as_uint(sqrtf(ks)));
  }
}

// ---------------------------------------------------------------------------
// Kernel 2: flash attention with FIXED per-row max (Cauchy-Schwarz bound).
// Block = 4 waves x 32 q-rows = 128 q-rows. No online-max/alpha/rescale:
// p = exp2(s - qn*kmax), l accumulated per-lane, reduced once at the end.
// ---------------------------------------------------------------------------
__global__ __launch_bounds__(256) void attn_kernel(
    const _Float16* __restrict__ Qh, const _Float16* __restrict__ Kh,
    const _Float16* __restrict__ Vh, const float* __restrict__ qn,
    const unsigned* __restrict__ kmaxu, _Float16* __restrict__ AO) {
  __shared__ char smem[36864];
  _Float16* Ks = (_Float16*)smem;            // [64][72]
  _Float16* Vt = (_Float16*)(smem + 9216);   // [64][72] (rows = d)
  _Float16* Ps = (_Float16*)(smem + 18432);  // [4 waves][32 q][72]
  float* Os = (float*)smem;                  // [128][68] epilogue reuse (34816 B)

  const int tid = threadIdx.x;
  const int lane = tid & 63;
  const int w = tid >> 6;
  const int m = lane & 15;
  const int quad = lane >> 4;
  const int bh = blockIdx.y;
  const int q0 = blockIdx.x * 128;

  const _Float16* Qb = Qh + (size_t)bh * NSEQ * DH;
  const _Float16* Kb = Kh + (size_t)bh * NSEQ * DH;
  const _Float16* Vb = Vh + (size_t)bh * DH * NSEQ;

  const int rA = q0 + w * 32 + m;      // q-group A rows
  const int rB = rA + 16;              // q-group B rows
  half8_t qfA0 = *(const half8_t*)(Qb + (size_t)rA * DH + quad * 8);
  half8_t qfA1 = *(const half8_t*)(Qb + (size_t)rA * DH + 32 + quad * 8);
  half8_t qfB0 = *(const half8_t*)(Qb + (size_t)rB * DH + quad * 8);
  half8_t qfB1 = *(const half8_t*)(Qb + (size_t)rB * DH + 32 + quad * 8);

  const float kmx = __uint_as_float(kmaxu[bh]);
  const float mA = qn[(size_t)bh * NSEQ + rA] * kmx;   // fixed row max (log2)
  const float mB = qn[(size_t)bh * NSEQ + rB] * kmx;

  float lA = 0.f, lB = 0.f;
  floatx4 OA[4], OB[4];
#pragma unroll
  for (int nb = 0; nb < 4; ++nb) {
    OA[nb] = (floatx4){0.f, 0.f, 0.f, 0.f};
    OB[nb] = (floatx4){0.f, 0.f, 0.f, 0.f};
  }

  _Float16* PwA = Ps + w * 2304 + m * 72;
  _Float16* PwB = PwA + 16 * 72;

  for (int ck = 0; ck < NSEQ / KC; ++ck) {
    const int k0 = ck * KC;
    __syncthreads();
    {  // stage K [key][d] and V^T [d][key]
      const _Float16* Kc = Kb + (size_t)k0 * DH;
      const _Float16* Vc = Vb + k0;
      int g = tid;
      int key = g >> 3, dg = g & 7;
      *(half8_t*)(Ks + key * 72 + dg * 8) = *(const half8_t*)(Kc + key * 64 + dg * 8);
      *(half8_t*)(Vt + key * 72 + dg * 8) = *(const half8_t*)(Vc + (size_t)key * NSEQ + dg * 8);
      g = tid + 256;
      key = g >> 3; dg = g & 7;
      *(half8_t*)(Ks + key * 72 + dg * 8) = *(const half8_t*)(Kc + key * 64 + dg * 8);
      *(half8_t*)(Vt + key * 72 + dg * 8) = *(const half8_t*)(Vc + (size_t)key * NSEQ + dg * 8);
    }
    __syncthreads();

    // S^T = K * Q^T for both q-groups (K-frags shared)
    floatx4 stA[4], stB[4];
#pragma unroll
    for (int kt = 0; kt < 4; ++kt) {
      half8_t kf0 = *(half8_t*)(Ks + (kt * 16 + m) * 72 + quad * 8);
      half8_t kf1 = *(half8_t*)(Ks + (kt * 16 + m) * 72 + 32 + quad * 8);
      floatx4 a = (floatx4){0.f, 0.f, 0.f, 0.f};
      a = __builtin_amdgcn_mfma_f32_16x16x32_f16(kf0, qfA0, a, 0, 0, 0);
      a = __builtin_amdgcn_mfma_f32_16x16x32_f16(kf1, qfA1, a, 0, 0, 0);
      stA[kt] = a;
      floatx4 b = (floatx4){0.f, 0.f, 0.f, 0.f};
      b = __builtin_amdgcn_mfma_f32_16x16x32_f16(kf0, qfB0, b, 0, 0, 0);
      b = __builtin_amdgcn_mfma_f32_16x16x32_f16(kf1, qfB1, b, 0, 0, 0);
      stB[kt] = b;
    }

    // p = exp2(s - m_fixed); accumulate l per-lane; pack fp16 -> Ps
#pragma unroll
    for (int kt = 0; kt < 4; ++kt) {
      half4_t phA, phB;
#pragma unroll
      for (int r = 0; r < 4; ++r) {
        const float pA = __builtin_exp2f(stA[kt][r] - mA);
        const float pB = __builtin_exp2f(stB[kt][r] - mB);
        lA += pA; lB += pB;
        phA[r] = (_Float16)pA; phB[r] = (_Float16)pB;
      }
      *(half4_t*)(PwA + kt * 16 + quad * 4) = phA;
      *(half4_t*)(PwB + kt * 16 + quad * 4) = phB;
    }

    // O += P * V (V-frags shared across q-groups)
#pragma unroll
    for (int c = 0; c < 2; ++c) {
      half8_t pfA = *(half8_t*)(PwA + c * 32 + quad * 8);
      half8_t pfB = *(half8_t*)(PwB + c * 32 + quad * 8);
#pragma unroll
      for (int nb = 0; nb < 4; ++nb) {
        half8_t vf = *(half8_t*)(Vt + (nb * 16 + m) * 72 + c * 32 + quad * 8);
        OA[nb] = __builtin_amdgcn_mfma_f32_16x16x32_f16(pfA, vf, OA[nb], 0, 0, 0);
        OB[nb] = __builtin_amdgcn_mfma_f32_16x16x32_f16(pfB, vf, OB[nb], 0, 0, 0);
      }
    }
  }

  // final l reduction (quads hold disjoint keys) and epilogue
  lA += __shfl_xor(lA, 16, 64); lA += __shfl_xor(lA, 32, 64);
  lB += __shfl_xor(lB, 16, 64); lB += __shfl_xor(lB, 32, 64);
  float lA4[4], lB4[4];
#pragma unroll
  for (int r = 0; r < 4; ++r) {
    lA4[r] = __shfl(lA, 4 * quad + r, 64);
    lB4[r] = __shfl(lB, 4 * quad + r, 64);
  }
  __syncthreads();
#pragma unroll
  for (int nb = 0; nb < 4; ++nb) {
#pragma unroll
    for (int r = 0; r < 4; ++r) {
      Os[(w * 32 + 4 * quad + r) * 68 + nb * 16 + m] = OA[nb][r] * (1.0f / lA4[r]);
      Os[(w * 32 + 16 + 4 * quad + r) * 68 + nb * 16 + m] = OB[nb][r] * (1.0f / lB4[r]);
    }
  }
  __syncthreads();
  const int ql = tid >> 1, dg = (tid & 1) * 32;
  const int b = bh >> 4, h = bh & 15;
  _Float16* dst = AO + ((size_t)(b * NSEQ + q0 + ql)) * CDIM + h * DH + dg;
#pragma unroll
  for (int u = 0; u < 4; ++u) {
    half8_t o;
#pragma unroll
    for (int v = 0; v < 8; ++v) o[v] = (_Float16)Os[ql * 68 + dg + u * 8 + v];
    *(half8_t*)(dst + u * 8) = o;
  }
}

// ---------------------------------------------------------------------------
// Kernel 3: proj GEMM (fp16 MFMA) + bias, fp32 out (unchanged R3).
// ---------------------------------------------------------------------------
__global__ __launch_bounds__(256) void proj_gemm_kernel(
    const _Float16* __restrict__ Ah, const _Float16* __restrict__ Wt,
    const float* __restrict__ bias, float* __restrict__ out) {
  __shared__ _Float16 As[128 * 64];
  __shared__ _Float16 Bs[128 * 64];
  const int tid = threadIdx.x;
  const int lane = tid & 63, w = tid >> 6;
  const int m = lane & 15, quad = lane >> 4;
  const int wr = (w >> 1) * 64, wc = (w & 1) * 64;
  const int m0 = blockIdx.y * 128;
  const int N0 = blockIdx.x * 128;
  const int sr = lane >> 3, sc = (lane & 7) * 8;

  floatx4 acc[4][4];
#pragma unroll
  for (int i = 0; i < 4; ++i)
#pragma unroll
    for (int j = 0; j < 4; ++j) acc[i][j] = (floatx4){0.f, 0.f, 0.f, 0.f};

  for (int k0 = 0; k0 < CDIM; k0 += 64) {
    __syncthreads();
#pragma unroll
    for (int i = 0; i < 4; ++i) {
      const int row = (w * 4 + i) * 8 + sr;
      __builtin_amdgcn_global_load_lds(
          GLOBAL_AS(Ah + (size_t)(m0 + row) * CDIM + k0 + sc),
          LDS_AS(As + (w * 4 + i) * 512), 16, 0, 0);
      __builtin_amdgcn_global_load_lds(
          GLOBAL_AS(Wt + (size_t)(N0 + row) * CDIM + k0 + sc),
          LDS_AS(Bs + (w * 4 + i) * 512), 16, 0, 0);
    }
    __syncthreads();
#pragma unroll
    for (int ks = 0; ks < 2; ++ks) {
      half8_t af[4], bf[4];
#pragma unroll
      for (int mt = 0; mt < 4; ++mt)
        af[mt] = *(half8_t*)(As + (wr + mt * 16 + m) * 64 + ks * 32 + quad * 8);
#pragma unroll
      for (int nt = 0; nt < 4; ++nt)
        bf[nt] = *(half8_t*)(Bs + (wc + nt * 16 + m) * 64 + ks * 32 + quad * 8);
#pragma unroll
      for (int mt = 0; mt < 4; ++mt)
#pragma unroll
        for (int nt = 0; nt < 4; ++nt)
          acc[mt][nt] = __builtin_amdgcn_mfma_f32_16x16x32_f16(
              af[mt], bf[nt], acc[mt][nt], 0, 0, 0);
    }
  }

  const int F0 = N0 + wc;
  float bv[4];
#pragma unroll
  for (int nt = 0; nt < 4; ++nt) bv[nt] = bias[F0 + nt * 16 + m];
#pragma unroll
  for (int mt = 0; mt < 4; ++mt)
#pragma unroll
    for (int reg = 0; reg < 4; ++reg) {
      const int gm = m0 + wr + mt * 16 + 4 * quad + reg;
#pragma unroll
      for (int nt = 0; nt < 4; ++nt)
        out[(size_t)gm * CDIM + F0 + nt * 16 + m] = acc[mt][nt][reg] + bv[nt];
    }
}

// ---------------------------------------------------------------------------
extern "C" void kernel_launch(void* const* d_in, const int* in_sizes, int n_in,
                              void* d_out, int out_size, void* d_ws, size_t ws_size,
                              hipStream_t stream) {
  const float* x     = (const float*)d_in[0];
  const float* Wqkv  = (const float*)d_in[1];
  const float* bqkv  = (const float*)d_in[2];
  const float* Wproj = (const float*)d_in[3];
  const float* bproj = (const float*)d_in[4];
  float* out = (float*)d_out;

  const size_t per = (size_t)BSZ * NH * NSEQ * DH;  // 8,388,608
  _Float16* xh  = (_Float16*)d_ws;
  _Float16* Wt  = xh + per;                 // [3072][1024]
  _Float16* Wpt = Wt + (size_t)3072 * 1024; // [1024][1024]
  _Float16* Qh  = Wpt + (size_t)1024 * 1024;
  _Float16* Kh  = Qh + per;
  _Float16* Vh  = Kh + per;
  _Float16* AOh = Vh + per;
  float*    qnp = (float*)(AOh + per);      // [64*2048] q-row norms
  unsigned* kmx = (unsigned*)(qnp + (size_t)64 * NSEQ);  // [64]

  cast_x_kernel<<<4096, 256, 0, stream>>>(x, xh);
  transpose_cast_kernel<<<dim3(48, 16), 256, 0, stream>>>(Wqkv, Wt, 1024, 3072);
  transpose_cast_kernel<<<dim3(16, 16), 256, 0, stream>>>(Wproj, Wpt, 1024, 1024);
  kmax_init_kernel<<<1, 64, 0, stream>>>(kmx);
  qkv_gemm_kernel<<<dim3(24, 64), 256, 0, stream>>>(xh, Wt, bqkv, Qh, Kh, Vh);
  qk_norms_kernel<<<4096, 256, 0, stream>>>(Qh, Kh, qnp, kmx);
  attn_kernel<<<dim3(16, 64), 256, 0, stream>>>(Qh, Kh, Vh, qnp, kmx, AOh);
  proj_gemm_kernel<<<dim3(8, 64), 256, 0, stream>>>(AOh, Wpt, bproj, out);
}

// Round 5
// 349.142 us; speedup vs baseline: 3.7026x; 3.7026x over previous
//
#include <hip/hip_runtime.h>
#include <hip/hip_bf16.h>
#include <math.h>

#define BSZ 4
#define NSEQ 2048
#define CDIM 1024
#define NH 16
#define DH 64
#define KC 64
#define KMAX_STRIDE 32   // one kmax slot per 128B cacheline

typedef _Float16 half8_t __attribute__((ext_vector_type(8)));
typedef _Float16 half4_t __attribute__((ext_vector_type(4)));
typedef float floatx4 __attribute__((ext_vector_type(4)));

#define GLOBAL_AS(p) ((const __attribute__((address_space(1))) void*)(p))
#define LDS_AS(p)    ((__attribute__((address_space(3))) void*)(p))

// ---------------------------------------------------------------------------
// Prep: fp32 -> fp16 casts (weights transposed to [N][K])
// ---------------------------------------------------------------------------
__global__ __launch_bounds__(256) void cast_x_kernel(
    const float* __restrict__ src, _Float16* __restrict__ dst) {
  const size_t i = ((size_t)blockIdx.x * 256 + threadIdx.x) * 8;
  float4 a = *(const float4*)(src + i);
  float4 b = *(const float4*)(src + i + 4);
  half8_t h;
  h[0] = (_Float16)a.x; h[1] = (_Float16)a.y; h[2] = (_Float16)a.z; h[3] = (_Float16)a.w;
  h[4] = (_Float16)b.x; h[5] = (_Float16)b.y; h[6] = (_Float16)b.z; h[7] = (_Float16)b.w;
  *(half8_t*)(dst + i) = h;
}

__global__ __launch_bounds__(256) void transpose_cast_kernel(
    const float* __restrict__ src, _Float16* __restrict__ dst, int R, int C) {
  __shared__ float Ls[64][65];
  const int t = threadIdx.x;
  const int r0 = blockIdx.y * 64, c0 = blockIdx.x * 64;
  {
    const int lr = t >> 2, lcg = (t & 3) * 16;
    const float* s = src + (size_t)(r0 + lr) * C + c0 + lcg;
#pragma unroll
    for (int u = 0; u < 4; ++u)
      *(float4*)&Ls[lr][lcg + 4 * u] = *(const float4*)(s + 4 * u);
  }
  __syncthreads();
  const int c = t >> 2, rg = (t & 3) * 16;
  half8_t h0, h1;
#pragma unroll
  for (int u = 0; u < 8; ++u) h0[u] = (_Float16)Ls[rg + u][c];
#pragma unroll
  for (int u = 0; u < 8; ++u) h1[u] = (_Float16)Ls[rg + 8 + u][c];
  _Float16* d = dst + (size_t)(c0 + c) * R + r0 + rg;
  *(half8_t*)d = h0;
  *(half8_t*)(d + 8) = h1;
}

// ---------------------------------------------------------------------------
// Kernel 1: QKV GEMM (fp16 MFMA) + bias + RoPE epilogue (unchanged R3).
// ---------------------------------------------------------------------------
__global__ __launch_bounds__(256) void qkv_gemm_kernel(
    const _Float16* __restrict__ xh, const _Float16* __restrict__ Wt,
    const float* __restrict__ bias, _Float16* __restrict__ Qh,
    _Float16* __restrict__ Kh, _Float16* __restrict__ Vh) {
  __shared__ _Float16 As[128 * 64];
  __shared__ _Float16 Bs[128 * 64];
  const int tid = threadIdx.x;
  const int lane = tid & 63, w = tid >> 6;
  const int m = lane & 15, quad = lane >> 4;
  const int wr = (w >> 1) * 64, wc = (w & 1) * 64;
  const int m0 = blockIdx.y * 128;
  const int N0 = blockIdx.x * 128;
  const int sr = lane >> 3, sc = (lane & 7) * 8;

  floatx4 acc[4][4];
#pragma unroll
  for (int i = 0; i < 4; ++i)
#pragma unroll
    for (int j = 0; j < 4; ++j) acc[i][j] = (floatx4){0.f, 0.f, 0.f, 0.f};

  for (int k0 = 0; k0 < CDIM; k0 += 64) {
    __syncthreads();
#pragma unroll
    for (int i = 0; i < 4; ++i) {
      const int row = (w * 4 + i) * 8 + sr;
      __builtin_amdgcn_global_load_lds(
          GLOBAL_AS(xh + (size_t)(m0 + row) * CDIM + k0 + sc),
          LDS_AS(As + (w * 4 + i) * 512), 16, 0, 0);
      __builtin_amdgcn_global_load_lds(
          GLOBAL_AS(Wt + (size_t)(N0 + row) * CDIM + k0 + sc),
          LDS_AS(Bs + (w * 4 + i) * 512), 16, 0, 0);
    }
    __syncthreads();
#pragma unroll
    for (int ks = 0; ks < 2; ++ks) {
      half8_t af[4], bf[4];
#pragma unroll
      for (int mt = 0; mt < 4; ++mt)
        af[mt] = *(half8_t*)(As + (wr + mt * 16 + m) * 64 + ks * 32 + quad * 8);
#pragma unroll
      for (int nt = 0; nt < 4; ++nt)
        bf[nt] = *(half8_t*)(Bs + (wc + nt * 16 + m) * 64 + ks * 32 + quad * 8);
#pragma unroll
      for (int mt = 0; mt < 4; ++mt)
#pragma unroll
        for (int nt = 0; nt < 4; ++nt)
          acc[mt][nt] = __builtin_amdgcn_mfma_f32_16x16x32_f16(
              af[mt], bf[nt], acc[mt][nt], 0, 0, 0);
    }
  }

  const int F0 = N0 + wc;
  const int which = F0 >> 10;
  const int head = (F0 & 1023) >> 6;
  float bv[4];
#pragma unroll
  for (int nt = 0; nt < 4; ++nt) bv[nt] = bias[F0 + nt * 16 + m];

  if (which == 2) {
#pragma unroll
    for (int mt = 0; mt < 4; ++mt)
#pragma unroll
      for (int reg = 0; reg < 4; ++reg) {
        const int gm = m0 + wr + mt * 16 + 4 * quad + reg;
        const int b = gm >> 11, n = gm & 2047;
        const size_t vbase = ((size_t)(b * NH + head) * DH) * NSEQ + n;
#pragma unroll
        for (int nt = 0; nt < 4; ++nt)
          Vh[vbase + (size_t)(nt * 16 + m) * NSEQ] =
              (_Float16)(acc[mt][nt][reg] + bv[nt]);
      }
  } else {
    _Float16* dst = which ? Kh : Qh;
    const float qs = which ? 1.0f : 0.125f * 1.4426950408889634f;
    const float invfA = expf(-9.210340371976184f * ((float)m * (1.0f / 32.0f)));
    const float invfB = expf(-9.210340371976184f * ((float)(16 + m) * (1.0f / 32.0f)));
#pragma unroll
    for (int mt = 0; mt < 4; ++mt)
#pragma unroll
      for (int reg = 0; reg < 4; ++reg) {
        const int gm = m0 + wr + mt * 16 + 4 * quad + reg;
        const int b = gm >> 11, n = gm & 2047;
        float sA, cA, sB, cB;
        sincosf((float)n * invfA, &sA, &cA);
        sincosf((float)n * invfB, &sB, &cB);
        const size_t obase = ((size_t)(b * NH + head) * NSEQ + n) * DH;
#pragma unroll
        for (int nt = 0; nt < 4; ++nt) {
          const float val = acc[mt][nt][reg] + bv[nt];
          const float rot = (nt < 2) ? -(acc[mt][nt + 2][reg] + bv[nt + 2])
                                     :  (acc[mt][nt - 2][reg] + bv[nt - 2]);
          const float sv = (nt & 1) ? sB : sA;
          const float cv = (nt & 1) ? cB : cA;
          dst[obase + nt * 16 + m] = (_Float16)((val * cv + rot * sv) * qs);
        }
      }
  }
}

// ---------------------------------------------------------------------------
// Norm prepass: qn[row] = ||Qh row||; kmax[bh] = max_n ||Kh row||.
// Block-level max reduction -> ONE atomicMax per block (4096 total,
// 64 per bh slot, slots padded to separate cachelines). R4's version did
// 131072 atomics onto 4 cachelines -> 939 us of serialized cross-XCD RMW.
// ---------------------------------------------------------------------------
__global__ __launch_bounds__(64) void kmax_init_kernel(unsigned* kmaxu) {
  for (int i = threadIdx.x; i < 64 * KMAX_STRIDE; i += 64) kmaxu[i] = 0u;
}

__global__ __launch_bounds__(256) void qk_norms_kernel(
    const _Float16* __restrict__ Qh, const _Float16* __restrict__ Kh,
    float* __restrict__ qn, unsigned* __restrict__ kmaxu) {
  __shared__ float wmax[4];
  const int tid = threadIdx.x;
  const size_t row = (size_t)blockIdx.x * 32 + (tid >> 3);  // 32 rows, one bh
  const int c = (tid & 7) * 8;
  half8_t q8 = *(const half8_t*)(Qh + row * DH + c);
  half8_t k8 = *(const half8_t*)(Kh + row * DH + c);
  float qs = 0.f, ks = 0.f;
#pragma unroll
  for (int u = 0; u < 8; ++u) {
    const float qv = (float)q8[u], kv = (float)k8[u];
    qs += qv * qv; ks += kv * kv;
  }
  // butterfly: all 8 lanes of a row-group end with the row totals
  qs += __shfl_xor(qs, 1, 64); ks += __shfl_xor(ks, 1, 64);
  qs += __shfl_xor(qs, 2, 64); ks += __shfl_xor(ks, 2, 64);
  qs += __shfl_xor(qs, 4, 64); ks += __shfl_xor(ks, 4, 64);
  if ((tid & 7) == 0) qn[row] = sqrtf(qs);
  // wave max over its 8 rows
  ks = fmaxf(ks, __shfl_xor(ks, 8, 64));
  ks = fmaxf(ks, __shfl_xor(ks, 16, 64));
  ks = fmaxf(ks, __shfl_xor(ks, 32, 64));
  if ((tid & 63) == 0) wmax[tid >> 6] = ks;
  __syncthreads();
  if (tid == 0) {
    const float mx = fmaxf(fmaxf(wmax[0], wmax[1]), fmaxf(wmax[2], wmax[3]));
    atomicMax(&kmaxu[(row >> 11) * KMAX_STRIDE], __float_as_uint(sqrtf(mx)));
  }
}

// ---------------------------------------------------------------------------
// Kernel 2: flash attention with FIXED per-row max (Cauchy-Schwarz bound).
// Block = 4 waves x 32 q-rows = 128 q-rows. No online-max/alpha/rescale.
// ---------------------------------------------------------------------------
__global__ __launch_bounds__(256) void attn_kernel(
    const _Float16* __restrict__ Qh, const _Float16* __restrict__ Kh,
    const _Float16* __restrict__ Vh, const float* __restrict__ qn,
    const unsigned* __restrict__ kmaxu, _Float16* __restrict__ AO) {
  __shared__ char smem[36864];
  _Float16* Ks = (_Float16*)smem;            // [64][72]
  _Float16* Vt = (_Float16*)(smem + 9216);   // [64][72] (rows = d)
  _Float16* Ps = (_Float16*)(smem + 18432);  // [4 waves][32 q][72]
  float* Os = (float*)smem;                  // [128][68] epilogue reuse

  const int tid = threadIdx.x;
  const int lane = tid & 63;
  const int w = tid >> 6;
  const int m = lane & 15;
  const int quad = lane >> 4;
  const int bh = blockIdx.y;
  const int q0 = blockIdx.x * 128;

  const _Float16* Qb = Qh + (size_t)bh * NSEQ * DH;
  const _Float16* Kb = Kh + (size_t)bh * NSEQ * DH;
  const _Float16* Vb = Vh + (size_t)bh * DH * NSEQ;

  const int rA = q0 + w * 32 + m;
  const int rB = rA + 16;
  half8_t qfA0 = *(const half8_t*)(Qb + (size_t)rA * DH + quad * 8);
  half8_t qfA1 = *(const half8_t*)(Qb + (size_t)rA * DH + 32 + quad * 8);
  half8_t qfB0 = *(const half8_t*)(Qb + (size_t)rB * DH + quad * 8);
  half8_t qfB1 = *(const half8_t*)(Qb + (size_t)rB * DH + 32 + quad * 8);

  const float kmx = __uint_as_float(kmaxu[bh * KMAX_STRIDE]);
  const float mA = qn[(size_t)bh * NSEQ + rA] * kmx;
  const float mB = qn[(size_t)bh * NSEQ + rB] * kmx;

  float lA = 0.f, lB = 0.f;
  floatx4 OA[4], OB[4];
#pragma unroll
  for (int nb = 0; nb < 4; ++nb) {
    OA[nb] = (floatx4){0.f, 0.f, 0.f, 0.f};
    OB[nb] = (floatx4){0.f, 0.f, 0.f, 0.f};
  }

  _Float16* PwA = Ps + w * 2304 + m * 72;
  _Float16* PwB = PwA + 16 * 72;

  for (int ck = 0; ck < NSEQ / KC; ++ck) {
    const int k0 = ck * KC;
    __syncthreads();
    {
      const _Float16* Kc = Kb + (size_t)k0 * DH;
      const _Float16* Vc = Vb + k0;
      int g = tid;
      int key = g >> 3, dg = g & 7;
      *(half8_t*)(Ks + key * 72 + dg * 8) = *(const half8_t*)(Kc + key * 64 + dg * 8);
      *(half8_t*)(Vt + key * 72 + dg * 8) = *(const half8_t*)(Vc + (size_t)key * NSEQ + dg * 8);
      g = tid + 256;
      key = g >> 3; dg = g & 7;
      *(half8_t*)(Ks + key * 72 + dg * 8) = *(const half8_t*)(Kc + key * 64 + dg * 8);
      *(half8_t*)(Vt + key * 72 + dg * 8) = *(const half8_t*)(Vc + (size_t)key * NSEQ + dg * 8);
    }
    __syncthreads();

    floatx4 stA[4], stB[4];
#pragma unroll
    for (int kt = 0; kt < 4; ++kt) {
      half8_t kf0 = *(half8_t*)(Ks + (kt * 16 + m) * 72 + quad * 8);
      half8_t kf1 = *(half8_t*)(Ks + (kt * 16 + m) * 72 + 32 + quad * 8);
      floatx4 a = (floatx4){0.f, 0.f, 0.f, 0.f};
      a = __builtin_amdgcn_mfma_f32_16x16x32_f16(kf0, qfA0, a, 0, 0, 0);
      a = __builtin_amdgcn_mfma_f32_16x16x32_f16(kf1, qfA1, a, 0, 0, 0);
      stA[kt] = a;
      floatx4 b = (floatx4){0.f, 0.f, 0.f, 0.f};
      b = __builtin_amdgcn_mfma_f32_16x16x32_f16(kf0, qfB0, b, 0, 0, 0);
      b = __builtin_amdgcn_mfma_f32_16x16x32_f16(kf1, qfB1, b, 0, 0, 0);
      stB[kt] = b;
    }

#pragma unroll
    for (int kt = 0; kt < 4; ++kt) {
      half4_t phA, phB;
#pragma unroll
      for (int r = 0; r < 4; ++r) {
        const float pA = __builtin_exp2f(stA[kt][r] - mA);
        const float pB = __builtin_exp2f(stB[kt][r] - mB);
        lA += pA; lB += pB;
        phA[r] = (_Float16)pA; phB[r] = (_Float16)pB;
      }
      *(half4_t*)(PwA + kt * 16 + quad * 4) = phA;
      *(half4_t*)(PwB + kt * 16 + quad * 4) = phB;
    }

#pragma unroll
    for (int c = 0; c < 2; ++c) {
      half8_t pfA = *(half8_t*)(PwA + c * 32 + quad * 8);
      half8_t pfB = *(half8_t*)(PwB + c * 32 + quad * 8);
#pragma unroll
      for (int nb = 0; nb < 4; ++nb) {
        half8_t vf = *(half8_t*)(Vt + (nb * 16 + m) * 72 + c * 32 + quad * 8);
        OA[nb] = __builtin_amdgcn_mfma_f32_16x16x32_f16(pfA, vf, OA[nb], 0, 0, 0);
        OB[nb] = __builtin_amdgcn_mfma_f32_16x16x32_f16(pfB, vf, OB[nb], 0, 0, 0);
      }
    }
  }

  lA += __shfl_xor(lA, 16, 64); lA += __shfl_xor(lA, 32, 64);
  lB += __shfl_xor(lB, 16, 64); lB += __shfl_xor(lB, 32, 64);
  float lA4[4], lB4[4];
#pragma unroll
  for (int r = 0; r < 4; ++r) {
    lA4[r] = __shfl(lA, 4 * quad + r, 64);
    lB4[r] = __shfl(lB, 4 * quad + r, 64);
  }
  __syncthreads();
#pragma unroll
  for (int nb = 0; nb < 4; ++nb) {
#pragma unroll
    for (int r = 0; r < 4; ++r) {
      Os[(w * 32 + 4 * quad + r) * 68 + nb * 16 + m] = OA[nb][r] * (1.0f / lA4[r]);
      Os[(w * 32 + 16 + 4 * quad + r) * 68 + nb * 16 + m] = OB[nb][r] * (1.0f / lB4[r]);
    }
  }
  __syncthreads();
  const int ql = tid >> 1, dg = (tid & 1) * 32;
  const int b = bh >> 4, h = bh & 15;
  _Float16* dst = AO + ((size_t)(b * NSEQ + q0 + ql)) * CDIM + h * DH + dg;
#pragma unroll
  for (int u = 0; u < 4; ++u) {
    half8_t o;
#pragma unroll
    for (int v = 0; v < 8; ++v) o[v] = (_Float16)Os[ql * 68 + dg + u * 8 + v];
    *(half8_t*)(dst + u * 8) = o;
  }
}

// ---------------------------------------------------------------------------
// Kernel 3: proj GEMM (fp16 MFMA) + bias, fp32 out (unchanged R3).
// ---------------------------------------------------------------------------
__global__ __launch_bounds__(256) void proj_gemm_kernel(
    const _Float16* __restrict__ Ah, const _Float16* __restrict__ Wt,
    const float* __restrict__ bias, float* __restrict__ out) {
  __shared__ _Float16 As[128 * 64];
  __shared__ _Float16 Bs[128 * 64];
  const int tid = threadIdx.x;
  const int lane = tid & 63, w = tid >> 6;
  const int m = lane & 15, quad = lane >> 4;
  const int wr = (w >> 1) * 64, wc = (w & 1) * 64;
  const int m0 = blockIdx.y * 128;
  const int N0 = blockIdx.x * 128;
  const int sr = lane >> 3, sc = (lane & 7) * 8;

  floatx4 acc[4][4];
#pragma unroll
  for (int i = 0; i < 4; ++i)
#pragma unroll
    for (int j = 0; j < 4; ++j) acc[i][j] = (floatx4){0.f, 0.f, 0.f, 0.f};

  for (int k0 = 0; k0 < CDIM; k0 += 64) {
    __syncthreads();
#pragma unroll
    for (int i = 0; i < 4; ++i) {
      const int row = (w * 4 + i) * 8 + sr;
      __builtin_amdgcn_global_load_lds(
          GLOBAL_AS(Ah + (size_t)(m0 + row) * CDIM + k0 + sc),
          LDS_AS(As + (w * 4 + i) * 512), 16, 0, 0);
      __builtin_amdgcn_global_load_lds(
          GLOBAL_AS(Wt + (size_t)(N0 + row) * CDIM + k0 + sc),
          LDS_AS(Bs + (w * 4 + i) * 512), 16, 0, 0);
    }
    __syncthreads();
#pragma unroll
    for (int ks = 0; ks < 2; ++ks) {
      half8_t af[4], bf[4];
#pragma unroll
      for (int mt = 0; mt < 4; ++mt)
        af[mt] = *(half8_t*)(As + (wr + mt * 16 + m) * 64 + ks * 32 + quad * 8);
#pragma unroll
      for (int nt = 0; nt < 4; ++nt)
        bf[nt] = *(half8_t*)(Bs + (wc + nt * 16 + m) * 64 + ks * 32 + quad * 8);
#pragma unroll
      for (int mt = 0; mt < 4; ++mt)
#pragma unroll
        for (int nt = 0; nt < 4; ++nt)
          acc[mt][nt] = __builtin_amdgcn_mfma_f32_16x16x32_f16(
              af[mt], bf[nt], acc[mt][nt], 0, 0, 0);
    }
  }

  const int F0 = N0 + wc;
  float bv[4];
#pragma unroll
  for (int nt = 0; nt < 4; ++nt) bv[nt] = bias[F0 + nt * 16 + m];
#pragma unroll
  for (int mt = 0; mt < 4; ++mt)
#pragma unroll
    for (int reg = 0; reg < 4; ++reg) {
      const int gm = m0 + wr + mt * 16 + 4 * quad + reg;
#pragma unroll
      for (int nt = 0; nt < 4; ++nt)
        out[(size_t)gm * CDIM + F0 + nt * 16 + m] = acc[mt][nt][reg] + bv[nt];
    }
}

// ---------------------------------------------------------------------------
extern "C" void kernel_launch(void* const* d_in, const int* in_sizes, int n_in,
                              void* d_out, int out_size, void* d_ws, size_t ws_size,
                              hipStream_t stream) {
  const float* x     = (const float*)d_in[0];
  const float* Wqkv  = (const float*)d_in[1];
  const float* bqkv  = (const float*)d_in[2];
  const float* Wproj = (const float*)d_in[3];
  const float* bproj = (const float*)d_in[4];
  float* out = (float*)d_out;

  const size_t per = (size_t)BSZ * NH * NSEQ * DH;  // 8,388,608
  _Float16* xh  = (_Float16*)d_ws;
  _Float16* Wt  = xh + per;                 // [3072][1024]
  _Float16* Wpt = Wt + (size_t)3072 * 1024; // [1024][1024]
  _Float16* Qh  = Wpt + (size_t)1024 * 1024;
  _Float16* Kh  = Qh + per;
  _Float16* Vh  = Kh + per;
  _Float16* AOh = Vh + per;
  float*    qnp = (float*)(AOh + per);      // [64*2048] q-row norms
  unsigned* kmx = (unsigned*)(qnp + (size_t)64 * NSEQ);  // [64*KMAX_STRIDE]

  cast_x_kernel<<<4096, 256, 0, stream>>>(x, xh);
  transpose_cast_kernel<<<dim3(48, 16), 256, 0, stream>>>(Wqkv, Wt, 1024, 3072);
  transpose_cast_kernel<<<dim3(16, 16), 256, 0, stream>>>(Wproj, Wpt, 1024, 1024);
  kmax_init_kernel<<<1, 64, 0, stream>>>(kmx);
  qkv_gemm_kernel<<<dim3(24, 64), 256, 0, stream>>>(xh, Wt, bqkv, Qh, Kh, Vh);
  qk_norms_kernel<<<4096, 256, 0, stream>>>(Qh, Kh, qnp, kmx);
  attn_kernel<<<dim3(16, 64), 256, 0, stream>>>(Qh, Kh, Vh, qnp, kmx, AOh);
  proj_gemm_kernel<<<dim3(8, 64), 256, 0, stream>>>(AOh, Wpt, bproj, out);
}